// Round 17
// baseline (41.834 us; speedup 1.0000x reference)
//
#include <hip/hip_runtime.h>

// BertWordEmbedder: B=64, T=512, H=768, W=256, D=256
// TWO kernels, no intermediate we:
//   prep_wt2: proj_w [768][256] f32 -> wt2 TILED bf16 [ct=16][kc=96][16col][8k]
//   fused:    R17 = R15 (32-word block, proven 36.0us) + 3-PASS INTERLEAVE:
//             pass j: pool col-third j of all pairs -> LDS region j; barrier;
//             GEMM chunk j (ks 8j..8j+8) on region j while next pass's HBM
//             loads issue. Disjoint LDS regions -> 1 barrier/pass. Keeps HBM
//             busy through the MFMA phases.
// Empty words: zero A row -> out = bias (matches reference).
// ws: [0) wt2 393216 B

#define NB 64
#define NT 512
#define NH 768
#define NW 256
#define ND 256
#define PAD 8
#define ROWE (NH + PAD)   // 776

typedef __attribute__((ext_vector_type(8))) short short8;
typedef __attribute__((ext_vector_type(4))) float f32x4;
typedef __attribute__((ext_vector_type(4))) float float4v;
typedef __attribute__((ext_vector_type(4))) unsigned short ushort4v;

__device__ __forceinline__ unsigned short f2bf(float f) {
    union { float f; unsigned u; } v; v.f = f;
    unsigned r = v.u + 0x7fffu + ((v.u >> 16) & 1u);  // RNE
    return (unsigned short)(r >> 16);
}

// proj_w -> tiled wt2 (CONTROL, R15-proven): (k,col) at
// [((col>>4)*96 + (k>>3))*16 + (col&15)]*8 + (k&7)
__global__ void prep_wt2(const float* __restrict__ w, unsigned short* __restrict__ wt2) {
    __shared__ float tile[32][33];
    const int tid = threadIdx.x, n = blockIdx.x;
    const int tx = tid & 31, ty = tid >> 5;
    const int k0 = (n % 24) * 32, n0 = (n / 24) * 32;
    #pragma unroll
    for (int i = 0; i < 4; ++i)
        tile[ty + 8 * i][tx] = w[(size_t)(k0 + ty + 8 * i) * ND + n0 + tx];
    __syncthreads();
    if (tid < 128) {
        const int cc = tid & 31, q = tid >> 5;
        const int col = n0 + cc;
        ushort4v u0, u1;
        #pragma unroll
        for (int j = 0; j < 4; ++j) u0[j] = f2bf(tile[q * 8 + j][cc]);
        #pragma unroll
        for (int j = 0; j < 4; ++j) u1[j] = f2bf(tile[q * 8 + 4 + j][cc]);
        size_t off = (((size_t)(col >> 4) * 96 + (k0 >> 3) + q) * 16 + (col & 15)) * 8;
        *(ushort4v*)&wt2[off]     = u0;
        *(ushort4v*)&wt2[off + 4] = u1;
    }
}

// fused pool+GEMM, 3-pass interleaved. 512 blocks = (b, 32-word group).
__global__ __launch_bounds__(256, 3)
void fused(const float* __restrict__ hs, const int* __restrict__ wid,
           const unsigned short* __restrict__ wt2, const float* __restrict__ pb,
           float* __restrict__ out) {
    __shared__ unsigned short A[32][ROWE];   // 49664 B
    __shared__ int swid[NT];
    __shared__ int sb[33];

    const int tid = threadIdx.x, bid = blockIdx.x;
    const int wave = tid >> 6, lane = tid & 63;
    const int b = bid >> 3, w0 = (bid & 7) * 32;

    swid[tid]       = wid[b * NT + tid];
    swid[tid + 256] = wid[b * NT + tid + 256];
    __syncthreads();
    if (tid <= 32) {
        int v = w0 + tid, lo = 0, hi = NT;
        while (lo < hi) { int mid = (lo + hi) >> 1; if (swid[mid] < v) lo = mid + 1; else hi = mid; }
        sb[tid] = lo;
    }
    __syncthreads();

    // GEMM state (persists across passes)
    const int cl = lane & 15, kg = lane >> 4;
    const int c0w = wave * 64;
    const unsigned short* bgp = wt2 + (size_t)(wave * 4) * 12288 + kg * 128 + cl * 8;
    short8 a0f, a1f, b0f[4], b1f[4];
    f32x4 acc[2][4];
    #pragma unroll
    for (int mt = 0; mt < 2; ++mt)
        #pragma unroll
        for (int nt = 0; nt < 4; ++nt)
            #pragma unroll
            for (int r = 0; r < 4; ++r) acc[mt][nt][r] = 0.f;

#define LDA2(d0, d1, ks) { d0 = *(const short8*)&A[cl][(ks) * 32 + kg * 8];   \
                           d1 = *(const short8*)&A[16 + cl][(ks) * 32 + kg * 8]; }
#define LDB(d, ks) { _Pragma("unroll")                                        \
                     for (int nt = 0; nt < 4; ++nt)                           \
                         d[nt] = *(const short8*)(bgp + nt * 12288 + (ks) * 512); }
#define MM2(aa0, aa1, bb) { _Pragma("unroll")                                 \
                    for (int nt = 0; nt < 4; ++nt) {                          \
                        acc[0][nt] = __builtin_amdgcn_mfma_f32_16x16x32_bf16(aa0, bb[nt], acc[0][nt], 0, 0, 0); \
                        acc[1][nt] = __builtin_amdgcn_mfma_f32_16x16x32_bf16(aa1, bb[nt], acc[1][nt], 0, 0, 0); } }

    const float* base0 = hs + (size_t)b * NT * NH + lane * 4;

    short8 a0b, a1b;   // second M-tile frags (ping-pong pairs)
    #pragma unroll 1
    for (int pass = 0; pass < 3; ++pass) {
        // ---- pool pass: col-third `pass` of all 4 pairs of this wave ----
        const float* base = base0 + pass * 256;
        #pragma unroll 1
        for (int pp = 0; pp < 4; ++pp) {
            const int p = wave * 4 + pp;
            const int s = sb[2 * p], m = sb[2 * p + 1], e = sb[2 * p + 2];
            float4v A0 = {0,0,0,0}, A1 = {0,0,0,0};
            int t = s;
            for (; t + 4 <= e; t += 4) {             // 4 x 1KB loads in flight
                float4v v0 = *(const float4v*)(base + (size_t)(t    ) * NH);
                float4v v1 = *(const float4v*)(base + (size_t)(t + 1) * NH);
                float4v v2 = *(const float4v*)(base + (size_t)(t + 2) * NH);
                float4v v3 = *(const float4v*)(base + (size_t)(t + 3) * NH);
                #pragma unroll
                for (int q = 0; q < 4; ++q) {
                    if (t     < m) A0[q] += v0[q]; else A1[q] += v0[q];
                }
                #pragma unroll
                for (int q = 0; q < 4; ++q) {
                    if (t + 1 < m) A0[q] += v1[q]; else A1[q] += v1[q];
                }
                #pragma unroll
                for (int q = 0; q < 4; ++q) {
                    if (t + 2 < m) A0[q] += v2[q]; else A1[q] += v2[q];
                }
                #pragma unroll
                for (int q = 0; q < 4; ++q) {
                    if (t + 3 < m) A0[q] += v3[q]; else A1[q] += v3[q];
                }
            }
            for (; t < e; ++t) {
                float4v v = *(const float4v*)(base + (size_t)t * NH);
                #pragma unroll
                for (int q = 0; q < 4; ++q) {
                    if (t < m) A0[q] += v[q]; else A1[q] += v[q];
                }
            }
            int c0n = m - s; if (c0n < 1) c0n = 1;
            int c1n = e - m; if (c1n < 1) c1n = 1;
            const float s0 = 1.0f / (float)c0n, s1 = 1.0f / (float)c1n;
            ushort4v u;
            #pragma unroll
            for (int q = 0; q < 4; ++q) u[q] = f2bf(A0[q] * s0);
            *(ushort4v*)&A[2 * p][pass * 256 + lane * 4] = u;
            #pragma unroll
            for (int q = 0; q < 4; ++q) u[q] = f2bf(A1[q] * s1);
            *(ushort4v*)&A[2 * p + 1][pass * 256 + lane * 4] = u;
        }
        __syncthreads();

        // ---- GEMM chunk: ks in [pass*8, pass*8+8) on LDS region `pass` ----
        const int ks0 = pass * 8;
        LDA2(a0f, a0b, ks0); LDB(b0f, ks0);
        #pragma unroll
        for (int i = 0; i < 4; ++i) {
            const int ks = ks0 + 2 * i;
            LDA2(a1f, a1b, ks + 1); LDB(b1f, ks + 1);
            MM2(a0f, a0b, b0f);
            if (i < 3) { LDA2(a0f, a0b, ks + 2); LDB(b0f, ks + 2); }
            MM2(a1f, a1b, b1f);
        }
        // no barrier needed: next pool pass writes a disjoint LDS region
    }
#undef LDA2
#undef LDB
#undef MM2

    float bv[4];
    #pragma unroll
    for (int nt = 0; nt < 4; ++nt) bv[nt] = pb[c0w + nt * 16 + cl];

    // C/D layout: col=lane&15, row=(lane>>4)*4+r  [proven R1-R16]
    #pragma unroll
    for (int mt = 0; mt < 2; ++mt)
        #pragma unroll
        for (int nt = 0; nt < 4; ++nt)
            #pragma unroll
            for (int r = 0; r < 4; ++r)
                out[((size_t)b * NW + w0 + mt * 16 + kg * 4 + r) * ND + c0w + nt * 16 + cl]
                    = acc[mt][nt][r] + bv[nt];
}

extern "C" void kernel_launch(void* const* d_in, const int* in_sizes, int n_in,
                              void* d_out, int out_size, void* d_ws, size_t ws_size,
                              hipStream_t stream) {
    const float* hs  = (const float*)d_in[0];
    const int*   wid = (const int*)d_in[1];
    const float* pw  = (const float*)d_in[2];
    const float* pb  = (const float*)d_in[3];
    float* out = (float*)d_out;

    unsigned short* wt2 = (unsigned short*)d_ws;     // 393216 B

    prep_wt2<<<192, 256, 0, stream>>>(pw, wt2);
    fused<<<NB * (NW / 32), 256, 0, stream>>>(hs, wid, wt2, pb, out);
}

// Round 18
// 35.494 us; speedup vs baseline: 1.1786x; 1.1786x over previous
//
#include <hip/hip_runtime.h>

// BertWordEmbedder: B=64, T=512, H=768, W=256, D=256
// TWO kernels, no intermediate we:
//   prep_wt2: proj_w [768][256] f32 -> wt2 TILED bf16 [ct=16][kc=96][16col][8k]
//   fused:    R18 = R15 geometry (block = (b, 32-word group) x full D) but
//             512 THREADS / 8 WAVES: phase A = 2 pairs/wave (half the serial
//             chain), 16 waves/CU resident (2x latency hiding). Phase B:
//             wave = 32x32 out tile (2Mx2N keeps B-frag reuse=2; block B
//             traffic stays 384 KB). Zero-barrier K-loop, ping-pong prefetch.
// Empty words: zero A row -> out = bias (matches reference).
// ws: [0) wt2 393216 B

#define NB 64
#define NT 512
#define NH 768
#define NW 256
#define ND 256
#define PAD 8
#define ROWE (NH + PAD)   // 776

typedef __attribute__((ext_vector_type(8))) short short8;
typedef __attribute__((ext_vector_type(4))) float f32x4;
typedef __attribute__((ext_vector_type(4))) float float4v;
typedef __attribute__((ext_vector_type(4))) unsigned short ushort4v;

__device__ __forceinline__ unsigned short f2bf(float f) {
    union { float f; unsigned u; } v; v.f = f;
    unsigned r = v.u + 0x7fffu + ((v.u >> 16) & 1u);  // RNE
    return (unsigned short)(r >> 16);
}

// proj_w -> tiled wt2 (CONTROL, R15-proven): (k,col) at
// [((col>>4)*96 + (k>>3))*16 + (col&15)]*8 + (k&7)
__global__ void prep_wt2(const float* __restrict__ w, unsigned short* __restrict__ wt2) {
    __shared__ float tile[32][33];
    const int tid = threadIdx.x, n = blockIdx.x;
    const int tx = tid & 31, ty = tid >> 5;
    const int k0 = (n % 24) * 32, n0 = (n / 24) * 32;
    #pragma unroll
    for (int i = 0; i < 4; ++i)
        tile[ty + 8 * i][tx] = w[(size_t)(k0 + ty + 8 * i) * ND + n0 + tx];
    __syncthreads();
    if (tid < 128) {
        const int cc = tid & 31, q = tid >> 5;
        const int col = n0 + cc;
        ushort4v u0, u1;
        #pragma unroll
        for (int j = 0; j < 4; ++j) u0[j] = f2bf(tile[q * 8 + j][cc]);
        #pragma unroll
        for (int j = 0; j < 4; ++j) u1[j] = f2bf(tile[q * 8 + 4 + j][cc]);
        size_t off = (((size_t)(col >> 4) * 96 + (k0 >> 3) + q) * 16 + (col & 15)) * 8;
        *(ushort4v*)&wt2[off]     = u0;
        *(ushort4v*)&wt2[off + 4] = u1;
    }
}

// fused pool+GEMM. 512 blocks = (b, 32-word group), 512 thr = 8 waves.
__global__ __launch_bounds__(512, 4)
void fused(const float* __restrict__ hs, const int* __restrict__ wid,
           const unsigned short* __restrict__ wt2, const float* __restrict__ pb,
           float* __restrict__ out) {
    __shared__ unsigned short A[32][ROWE];   // 49664 B
    __shared__ int swid[NT];
    __shared__ int sb[33];

    const int tid = threadIdx.x, bid = blockIdx.x;
    const int wave = tid >> 6, lane = tid & 63;
    const int b = bid >> 3, w0 = (bid & 7) * 32;

    // stage word ids (512 thr -> 1 each); parallel bounds (33 searches)
    swid[tid] = wid[b * NT + tid];
    __syncthreads();
    if (tid <= 32) {
        int v = w0 + tid, lo = 0, hi = NT;
        while (lo < hi) { int mid = (lo + hi) >> 1; if (swid[mid] < v) lo = mid + 1; else hi = mid; }
        sb[tid] = lo;
    }
    __syncthreads();

    // ---- Phase A: pool 16 word-pairs (R8-proven streaming), 2 pairs/wave ----
    const float* base = hs + (size_t)b * NT * NH + lane * 4;
    #pragma unroll 1
    for (int pp = 0; pp < 2; ++pp) {
        const int p = wave * 2 + pp;                 // pair 0..15, rows 2p,2p+1
        const int s = sb[2 * p], m = sb[2 * p + 1], e = sb[2 * p + 2];

        float4v a0c0 = {0,0,0,0}, a0c1 = {0,0,0,0}, a0c2 = {0,0,0,0};
        float4v a1c0 = {0,0,0,0}, a1c1 = {0,0,0,0}, a1c2 = {0,0,0,0};
#define ROUTE(t, v0, v1, v2) {                                                \
        if ((t) < m) {                                                        \
            _Pragma("unroll") for (int q = 0; q < 4; ++q) {                   \
                a0c0[q] += (v0)[q]; a0c1[q] += (v1)[q]; a0c2[q] += (v2)[q]; } \
        } else {                                                              \
            _Pragma("unroll") for (int q = 0; q < 4; ++q) {                   \
                a1c0[q] += (v0)[q]; a1c1[q] += (v1)[q]; a1c2[q] += (v2)[q]; } \
        }                                                                     \
    }
        int t = s;
        for (; t + 2 <= e; t += 2) {                 // 6 loads in flight
            float4v v[2][3];
            #pragma unroll
            for (int u = 0; u < 2; ++u) {
                const float* p2 = base + (size_t)(t + u) * NH;
                v[u][0] = *(const float4v*)(p2);
                v[u][1] = *(const float4v*)(p2 + 256);
                v[u][2] = *(const float4v*)(p2 + 512);
            }
            #pragma unroll
            for (int u = 0; u < 2; ++u) ROUTE(t + u, v[u][0], v[u][1], v[u][2]);
        }
        if (t < e) {
            const float* p2 = base + (size_t)t * NH;
            float4v v0 = *(const float4v*)(p2);
            float4v v1 = *(const float4v*)(p2 + 256);
            float4v v2 = *(const float4v*)(p2 + 512);
            ROUTE(t, v0, v1, v2);
        }
#undef ROUTE
        int c0n = m - s; if (c0n < 1) c0n = 1;
        int c1n = e - m; if (c1n < 1) c1n = 1;
        const float s0 = 1.0f / (float)c0n, s1 = 1.0f / (float)c1n;
        ushort4v u;
        #pragma unroll
        for (int q = 0; q < 4; ++q) u[q] = f2bf(a0c0[q] * s0);
        *(ushort4v*)&A[2 * p][lane * 4] = u;
        #pragma unroll
        for (int q = 0; q < 4; ++q) u[q] = f2bf(a0c1[q] * s0);
        *(ushort4v*)&A[2 * p][256 + lane * 4] = u;
        #pragma unroll
        for (int q = 0; q < 4; ++q) u[q] = f2bf(a0c2[q] * s0);
        *(ushort4v*)&A[2 * p][512 + lane * 4] = u;
        #pragma unroll
        for (int q = 0; q < 4; ++q) u[q] = f2bf(a1c0[q] * s1);
        *(ushort4v*)&A[2 * p + 1][lane * 4] = u;
        #pragma unroll
        for (int q = 0; q < 4; ++q) u[q] = f2bf(a1c1[q] * s1);
        *(ushort4v*)&A[2 * p + 1][256 + lane * 4] = u;
        #pragma unroll
        for (int q = 0; q < 4; ++q) u[q] = f2bf(a1c2[q] * s1);
        *(ushort4v*)&A[2 * p + 1][512 + lane * 4] = u;
    }
    __syncthreads();

    // ---- Phase B: GEMM [32x768]x[768x256]; wave = 32x32 (2Mx2N) ----
    const int cl = lane & 15, kg = lane >> 4;
    const int c0w = wave * 32;
    const unsigned short* bgp = wt2 + (size_t)(wave * 2) * 12288 + kg * 128 + cl * 8;

    short8 a0f[2], a1f[2], b0f[2], b1f[2];
    f32x4 acc[2][2];
    #pragma unroll
    for (int mt = 0; mt < 2; ++mt)
        #pragma unroll
        for (int nt = 0; nt < 2; ++nt)
            #pragma unroll
            for (int r = 0; r < 4; ++r) acc[mt][nt][r] = 0.f;

#define LDA(d, ks) { d[0] = *(const short8*)&A[cl][(ks) * 32 + kg * 8];       \
                     d[1] = *(const short8*)&A[16 + cl][(ks) * 32 + kg * 8]; }
#define LDB(d, ks) { _Pragma("unroll")                                        \
                     for (int nt = 0; nt < 2; ++nt)                           \
                         d[nt] = *(const short8*)(bgp + nt * 12288 + (ks) * 512); }
#define MM(a, bb) { _Pragma("unroll")                                         \
                    for (int mt = 0; mt < 2; ++mt)                            \
                        _Pragma("unroll")                                     \
                        for (int nt = 0; nt < 2; ++nt)                        \
                            acc[mt][nt] = __builtin_amdgcn_mfma_f32_16x16x32_bf16(a[mt], bb[nt], acc[mt][nt], 0, 0, 0); }

    LDA(a0f, 0); LDB(b0f, 0);
    #pragma unroll 1
    for (int i = 0; i < 12; ++i) {
        const int ks = 2 * i;
        LDA(a1f, ks + 1); LDB(b1f, ks + 1);
        MM(a0f, b0f);
        if (i < 11) { LDA(a0f, ks + 2); LDB(b0f, ks + 2); }
        MM(a1f, b1f);
    }
#undef LDA
#undef LDB
#undef MM

    float bv[2];
    bv[0] = pb[c0w + cl];
    bv[1] = pb[c0w + 16 + cl];

    // C/D layout: col=lane&15, row=(lane>>4)*4+r  [proven R1-R17]
    #pragma unroll
    for (int mt = 0; mt < 2; ++mt)
        #pragma unroll
        for (int nt = 0; nt < 2; ++nt)
            #pragma unroll
            for (int r = 0; r < 4; ++r)
                out[((size_t)b * NW + w0 + mt * 16 + kg * 4 + r) * ND + c0w + nt * 16 + cl]
                    = acc[mt][nt][r] + bv[nt];
}

extern "C" void kernel_launch(void* const* d_in, const int* in_sizes, int n_in,
                              void* d_out, int out_size, void* d_ws, size_t ws_size,
                              hipStream_t stream) {
    const float* hs  = (const float*)d_in[0];
    const int*   wid = (const int*)d_in[1];
    const float* pw  = (const float*)d_in[2];
    const float* pb  = (const float*)d_in[3];
    float* out = (float*)d_out;

    unsigned short* wt2 = (unsigned short*)d_ws;     // 393216 B

    prep_wt2<<<192, 256, 0, stream>>>(pw, wt2);
    fused<<<NB * (NW / 32), 512, 0, stream>>>(hs, wid, wt2, pb, out);
}

// Round 19
// 35.391 us; speedup vs baseline: 1.1820x; 1.0029x over previous
//
#include <hip/hip_runtime.h>

// BertWordEmbedder: B=64, T=512, H=768, W=256, D=256
// TWO kernels, no intermediate we:
//   prep_wt2: proj_w [768][256] f32 -> wt2 TILED bf16 [ct=16][kc=96][16col][8k]
//   fused:    R19 = R18 (512 thr / 8 waves, best 35.5us) but phase A processes
//             each wave's FULL 4-word token range as ONE stream: 4-token unroll
//             (12 loads in flight), 4-way uniform routing into 4 accumulator
//             sets, ONE pipeline drain per wave (was one per pair).
//             Phase B: wave = 32x32 (2Mx2N), zero-barrier K-loop (unchanged).
// Empty words: zero A row -> out = bias (matches reference).
// ws: [0) wt2 393216 B

#define NB 64
#define NT 512
#define NH 768
#define NW 256
#define ND 256
#define PAD 8
#define ROWE (NH + PAD)   // 776

typedef __attribute__((ext_vector_type(8))) short short8;
typedef __attribute__((ext_vector_type(4))) float f32x4;
typedef __attribute__((ext_vector_type(4))) float float4v;
typedef __attribute__((ext_vector_type(4))) unsigned short ushort4v;

__device__ __forceinline__ unsigned short f2bf(float f) {
    union { float f; unsigned u; } v; v.f = f;
    unsigned r = v.u + 0x7fffu + ((v.u >> 16) & 1u);  // RNE
    return (unsigned short)(r >> 16);
}

// proj_w -> tiled wt2 (CONTROL, R15-proven): (k,col) at
// [((col>>4)*96 + (k>>3))*16 + (col&15)]*8 + (k&7)
__global__ void prep_wt2(const float* __restrict__ w, unsigned short* __restrict__ wt2) {
    __shared__ float tile[32][33];
    const int tid = threadIdx.x, n = blockIdx.x;
    const int tx = tid & 31, ty = tid >> 5;
    const int k0 = (n % 24) * 32, n0 = (n / 24) * 32;
    #pragma unroll
    for (int i = 0; i < 4; ++i)
        tile[ty + 8 * i][tx] = w[(size_t)(k0 + ty + 8 * i) * ND + n0 + tx];
    __syncthreads();
    if (tid < 128) {
        const int cc = tid & 31, q = tid >> 5;
        const int col = n0 + cc;
        ushort4v u0, u1;
        #pragma unroll
        for (int j = 0; j < 4; ++j) u0[j] = f2bf(tile[q * 8 + j][cc]);
        #pragma unroll
        for (int j = 0; j < 4; ++j) u1[j] = f2bf(tile[q * 8 + 4 + j][cc]);
        size_t off = (((size_t)(col >> 4) * 96 + (k0 >> 3) + q) * 16 + (col & 15)) * 8;
        *(ushort4v*)&wt2[off]     = u0;
        *(ushort4v*)&wt2[off + 4] = u1;
    }
}

// fused pool+GEMM. 512 blocks = (b, 32-word group), 512 thr = 8 waves.
__global__ __launch_bounds__(512, 4)
void fused(const float* __restrict__ hs, const int* __restrict__ wid,
           const unsigned short* __restrict__ wt2, const float* __restrict__ pb,
           float* __restrict__ out) {
    __shared__ unsigned short A[32][ROWE];   // 49664 B
    __shared__ int swid[NT];
    __shared__ int sb[33];

    const int tid = threadIdx.x, bid = blockIdx.x;
    const int wave = tid >> 6, lane = tid & 63;
    const int b = bid >> 3, w0 = (bid & 7) * 32;

    swid[tid] = wid[b * NT + tid];
    __syncthreads();
    if (tid <= 32) {
        int v = w0 + tid, lo = 0, hi = NT;
        while (lo < hi) { int mid = (lo + hi) >> 1; if (swid[mid] < v) lo = mid + 1; else hi = mid; }
        sb[tid] = lo;
    }
    __syncthreads();

    // ---- Phase A: wave owns words 4w..4w+3 as ONE token stream ----
    const float* base = hs + (size_t)b * NT * NH + lane * 4;
    {
        const int s0 = sb[wave * 4],     s1 = sb[wave * 4 + 1];
        const int s2 = sb[wave * 4 + 2], s3 = sb[wave * 4 + 3];
        const int s4 = sb[wave * 4 + 4];

        float4v acc[4][3];
        #pragma unroll
        for (int r = 0; r < 4; ++r)
            #pragma unroll
            for (int c = 0; c < 3; ++c)
                #pragma unroll
                for (int q = 0; q < 4; ++q) acc[r][c][q] = 0.f;

#define ADD3(ar, vv) { _Pragma("unroll")                                      \
        for (int q = 0; q < 4; ++q) {                                         \
            ar[0][q] += (vv)[0][q]; ar[1][q] += (vv)[1][q]; ar[2][q] += (vv)[2][q]; } }
#define ROUTE4(tt, vv) {                                                      \
        if ((tt) < s1)      { ADD3(acc[0], vv); }                             \
        else if ((tt) < s2) { ADD3(acc[1], vv); }                             \
        else if ((tt) < s3) { ADD3(acc[2], vv); }                             \
        else                { ADD3(acc[3], vv); } }

        int t = s0;
        for (; t + 4 <= s4; t += 4) {                // 12 x 1KB loads in flight
            float4v v[4][3];
            #pragma unroll
            for (int u = 0; u < 4; ++u) {
                const float* p2 = base + (size_t)(t + u) * NH;
                v[u][0] = *(const float4v*)(p2);
                v[u][1] = *(const float4v*)(p2 + 256);
                v[u][2] = *(const float4v*)(p2 + 512);
            }
            #pragma unroll
            for (int u = 0; u < 4; ++u) ROUTE4(t + u, v[u]);
        }
        for (; t < s4; ++t) {
            float4v v1[3];
            const float* p2 = base + (size_t)t * NH;
            v1[0] = *(const float4v*)(p2);
            v1[1] = *(const float4v*)(p2 + 256);
            v1[2] = *(const float4v*)(p2 + 512);
            ROUTE4(t, v1);
        }
#undef ROUTE4
#undef ADD3

        // scale + convert + LDS write, one row per word
        #pragma unroll
        for (int r = 0; r < 4; ++r) {
            const int row = wave * 4 + r;
            int cs = (r == 0) ? s0 : (r == 1) ? s1 : (r == 2) ? s2 : s3;
            int ce = (r == 0) ? s1 : (r == 1) ? s2 : (r == 2) ? s3 : s4;
            int cnt = ce - cs; if (cnt < 1) cnt = 1;
            const float sc = 1.0f / (float)cnt;
            #pragma unroll
            for (int c = 0; c < 3; ++c) {
                ushort4v u;
                #pragma unroll
                for (int q = 0; q < 4; ++q) u[q] = f2bf(acc[r][c][q] * sc);
                *(ushort4v*)&A[row][c * 256 + lane * 4] = u;
            }
        }
    }
    __syncthreads();

    // ---- Phase B: GEMM [32x768]x[768x256]; wave = 32x32 (2Mx2N)  [R18] ----
    const int cl = lane & 15, kg = lane >> 4;
    const int c0w = wave * 32;
    const unsigned short* bgp = wt2 + (size_t)(wave * 2) * 12288 + kg * 128 + cl * 8;

    short8 a0f[2], a1f[2], b0f[2], b1f[2];
    f32x4 acc[2][2];
    #pragma unroll
    for (int mt = 0; mt < 2; ++mt)
        #pragma unroll
        for (int nt = 0; nt < 2; ++nt)
            #pragma unroll
            for (int r = 0; r < 4; ++r) acc[mt][nt][r] = 0.f;

#define LDA(d, ks) { d[0] = *(const short8*)&A[cl][(ks) * 32 + kg * 8];       \
                     d[1] = *(const short8*)&A[16 + cl][(ks) * 32 + kg * 8]; }
#define LDB(d, ks) { _Pragma("unroll")                                        \
                     for (int nt = 0; nt < 2; ++nt)                           \
                         d[nt] = *(const short8*)(bgp + nt * 12288 + (ks) * 512); }
#define MM(a, bb) { _Pragma("unroll")                                         \
                    for (int mt = 0; mt < 2; ++mt)                            \
                        _Pragma("unroll")                                     \
                        for (int nt = 0; nt < 2; ++nt)                        \
                            acc[mt][nt] = __builtin_amdgcn_mfma_f32_16x16x32_bf16(a[mt], bb[nt], acc[mt][nt], 0, 0, 0); }

    LDA(a0f, 0); LDB(b0f, 0);
    #pragma unroll 1
    for (int i = 0; i < 12; ++i) {
        const int ks = 2 * i;
        LDA(a1f, ks + 1); LDB(b1f, ks + 1);
        MM(a0f, b0f);
        if (i < 11) { LDA(a0f, ks + 2); LDB(b0f, ks + 2); }
        MM(a1f, b1f);
    }
#undef LDA
#undef LDB
#undef MM

    float bv[2];
    bv[0] = pb[c0w + cl];
    bv[1] = pb[c0w + 16 + cl];

    // C/D layout: col=lane&15, row=(lane>>4)*4+r  [proven R1-R18]
    #pragma unroll
    for (int mt = 0; mt < 2; ++mt)
        #pragma unroll
        for (int nt = 0; nt < 2; ++nt)
            #pragma unroll
            for (int r = 0; r < 4; ++r)
                out[((size_t)b * NW + w0 + mt * 16 + kg * 4 + r) * ND + c0w + nt * 16 + cl]
                    = acc[mt][nt][r] + bv[nt];
}

extern "C" void kernel_launch(void* const* d_in, const int* in_sizes, int n_in,
                              void* d_out, int out_size, void* d_ws, size_t ws_size,
                              hipStream_t stream) {
    const float* hs  = (const float*)d_in[0];
    const int*   wid = (const int*)d_in[1];
    const float* pw  = (const float*)d_in[2];
    const float* pb  = (const float*)d_in[3];
    float* out = (float*)d_out;

    unsigned short* wt2 = (unsigned short*)d_ws;     // 393216 B

    prep_wt2<<<192, 256, 0, stream>>>(pw, wt2);
    fused<<<NB * (NW / 32), 512, 0, stream>>>(hs, wid, wt2, pb, out);
}